// Round 7
// baseline (139.948 us; speedup 1.0000x reference)
//
#include <hip/hip_runtime.h>
#include <math.h>

#define Bn 8
#define Hn 256
#define Wn 256
#define HW (Hn * Wn)

typedef __attribute__((ext_vector_type(8))) short bf16x8;
typedef __attribute__((ext_vector_type(4))) float f32x4;

// Pack two fp32 into packed bf16x2 by TRUNCATION using one v_perm_b32.
// D[15:0] = lo[31:16], D[31:16] = hi[31:16]. (<=1 ulp err vs 0.5 for RNE;
// absmax headroom is ~6x, R6 measured 0.0156 with RNE.)
__device__ __forceinline__ unsigned int pk_bf16(float lo, float hi) {
  return __builtin_amdgcn_perm(__float_as_uint(hi), __float_as_uint(lo),
                               0x07060302u);
}

// Kernel A (R7): fused per-neighbor conv1(2->64,3x3)+ReLU -> conv2(64->1)
// -> sigmoid -> gate, conv1 on bf16 MFMA (K=18 padded to 32).
//
// R7 changes vs R6 (which had 2.26M LDS bank conflicts + heavy pack VALU):
//  - im2col LDS split into per-quad regions imq[q][px] (16 B contiguous per
//    px): every ds_read/ds_write_b128 is stride-1 within each 16-lane
//    group -> conflict-free (R6's 80 B stride collided 8-way).
//  - bf16 packing via 1x v_perm_b32 per pair (truncation) instead of ~5-op
//    manual RNE: im2col pack 45->9 instr, weight pack 20->4.
//  - epilogue: all 4 strips' gates kept in regs (lane-replicated after the
//    quad reduce), then ONE coalesced 64-lane store (R6 did 4 divergent
//    lane<16 stores).
//  - W2/b1 vector loads issued before the barrier.
__global__ __launch_bounds__(256) void sim_kernel(
    const float* __restrict__ x,   // (8,7,256,256)
    const float* __restrict__ W1,  // (6,64,2,3,3)
    const float* __restrict__ b1,  // (6,64)
    const float* __restrict__ W2,  // (6,1,64,1,1)
    const float* __restrict__ b2,  // (6,1)
    float* __restrict__ comb)      // (8,7,256,256)
{
  __shared__ uint4 imq[4][256];  // 16 KB: imq[q][px] = k[8q..8q+7] bf16
  __shared__ uint4 wq[4][64];    // 4 KB:  wq[f][q*16+m] = A-frag 16 B
  __shared__ float ccfp[256];    // fp32 check-center per px

  int bi = blockIdx.x;
  int n = bi >> 11;          // 0..5
  int b = (bi >> 8) & 7;     // 0..7
  int h = bi & 255;          // 0..255
  int cc = (n < 3) ? n : n + 1;
  int t = threadIdx.x;

  const float* xb     = x + (size_t)b * 7 * HW;
  const float* basep  = xb + 3 * HW;
  const float* checkp = xb + (size_t)cc * HW;

  // ---- stage A (weights) in MFMA A-layout: t = f*64 + q*16 + m ----
  {
    int f = t >> 6, q = (t >> 4) & 3, m = t & 15;
    int ch = 16 * f + m;
    int bsrc = (n < 3) ? 0 : 1;  // weight input-ch that multiplies BASE
    const float* wch = W1 + ((size_t)(n * 64 + ch)) * 18;  // [src][tap0..8]
    unsigned int kv[4];
#pragma unroll
    for (int jj = 0; jj < 4; ++jj) {
      int k0 = q * 8 + jj * 2, k1 = k0 + 1;
      float v0 = 0.f, v1 = 0.f;
      if (k0 < 18) {
        int src = (k0 < 9) ? bsrc : 1 - bsrc;
        v0 = wch[src * 9 + (k0 < 9 ? k0 : k0 - 9)];
      }
      if (k1 < 18) {
        int src = (k1 < 9) ? bsrc : 1 - bsrc;
        v1 = wch[src * 9 + (k1 < 9 ? k1 : k1 - 9)];
      }
      kv[jj] = pk_bf16(v0, v1);
    }
    wq[f][(q << 4) + m] = make_uint4(kv[0], kv[1], kv[2], kv[3]);
  }

  // ---- per-lane conv2/bias params: load BEFORE barrier (global, no LDS dep)
  int lane = t & 63, wv = t >> 6;
  int q = lane >> 4, m_ = lane & 15;
  float w2v[4][4], b1v[4][4];
#pragma unroll
  for (int f = 0; f < 4; ++f) {
    float4 tw = *(const float4*)&W2[n * 64 + 16 * f + 4 * q];
    float4 tb = *(const float4*)&b1[n * 64 + 16 * f + 4 * q];
    w2v[f][0] = tw.x; w2v[f][1] = tw.y; w2v[f][2] = tw.z; w2v[f][3] = tw.w;
    b1v[f][0] = tb.x; b1v[f][1] = tb.y; b1v[f][2] = tb.z; b1v[f][3] = tb.w;
  }
  float bb = b2[n];

  // ---- stage B (im2col) for pixel px = t ----
  {
    float v[18];  // k = pl*9 + r*3 + dx; pl0 = base, pl1 = check
#pragma unroll
    for (int pl = 0; pl < 2; ++pl) {
      const float* plane = pl ? checkp : basep;
#pragma unroll
      for (int r = 0; r < 3; ++r) {
        int hh = h - 1 + r;
        bool okh = (unsigned)hh < (unsigned)Hn;
        const float* row = plane + hh * Wn;
#pragma unroll
        for (int dx = 0; dx < 3; ++dx) {
          int c = t - 1 + dx;
          bool ok = okh && ((unsigned)c < (unsigned)Wn);
          v[pl * 9 + r * 3 + dx] = ok ? row[c] : 0.f;
        }
      }
    }
    ccfp[t] = v[13];  // check center (fp32, for gating)
    if (n == 0) {     // combined channel 3 = base plane (center)
      comb[((size_t)b * 7 + 3) * HW + h * Wn + t] = v[4];
    }
    unsigned int kv[9];
#pragma unroll
    for (int j = 0; j < 9; ++j) kv[j] = pk_bf16(v[2 * j], v[2 * j + 1]);
    imq[0][t] = make_uint4(kv[0], kv[1], kv[2], kv[3]);
    imq[1][t] = make_uint4(kv[4], kv[5], kv[6], kv[7]);
    imq[2][t] = make_uint4(kv[8], 0u, 0u, 0u);
    imq[3][t] = make_uint4(0u, 0u, 0u, 0u);
  }
  __syncthreads();

  // A fragments: contiguous 16 B per lane -> conflict-free
  bf16x8 afrag[4];
#pragma unroll
  for (int f = 0; f < 4; ++f) afrag[f] = *(const bf16x8*)&wq[f][lane];

  float* combcc = comb + ((size_t)b * 7 + cc) * HW + h * Wn;

  float g[4];
#pragma unroll
  for (int i = 0; i < 4; ++i) {
    int s = wv * 4 + i;        // strip 0..15
    int px = s * 16 + m_;      // this lane's pixel column

    f32x4 acc[4];
#pragma unroll
    for (int f = 0; f < 4; ++f) {
      acc[f][0] = b1v[f][0]; acc[f][1] = b1v[f][1];
      acc[f][2] = b1v[f][2]; acc[f][3] = b1v[f][3];
    }

    bf16x8 bfrag = *(const bf16x8*)&imq[q][px];  // stride-1 in each quad
#pragma unroll
    for (int f = 0; f < 4; ++f)
      acc[f] = __builtin_amdgcn_mfma_f32_16x16x32_bf16(afrag[f], bfrag,
                                                       acc[f], 0, 0, 0);

    // conv2 (1x1): per-lane partial over its 16 channels, then quad-reduce
    float sp = 0.f;
#pragma unroll
    for (int f = 0; f < 4; ++f)
#pragma unroll
      for (int r = 0; r < 4; ++r)
        sp = fmaf(w2v[f][r], fmaxf(acc[f][r], 0.f), sp);
    sp += __shfl_xor(sp, 16, 64);
    sp += __shfl_xor(sp, 32, 64);
    sp += bb;

    float e = __builtin_amdgcn_exp2f(sp * -1.442695041f);
    g[i] = __builtin_amdgcn_rcpf(1.f + e);
  }

  // Coalesced store: lane l handles px = wv*64 + l, whose gate is g[l>>4]
  // (g[] is lane-replicated across quads after the shfl reduce).
  int hi = lane >> 4;
  float gsel = (hi == 0) ? g[0] : (hi == 1) ? g[1] : (hi == 2) ? g[2] : g[3];
  int pxs = wv * 64 + lane;
  combcc[pxs] = gsel * ccfp[pxs];
}

// Kernel B: final mixing conv (7->7, 3x3, SAME). 2 px/thread, 1024 blocks.
// (Unchanged from R5 — never appears in top-5 dispatches; the total-minus-sim
// gap is ~constant across variants => fixed harness overhead.)
__global__ __launch_bounds__(256) void mix_kernel(
    const float* __restrict__ comb,  // (8,7,256,256)
    const float* __restrict__ Wm,    // (7,7,3,3)
    const float* __restrict__ bm,    // (7,)
    float* __restrict__ out)         // (8,7,256,256)
{
  int idx = blockIdx.x * 256 + threadIdx.x;  // over B*H*W/2 = 262144
  int w0 = (idx & 127) << 1;
  int h  = (idx >> 7) & (Hn - 1);
  int b  = idx >> 15;
  const float* cbase = comb + (size_t)b * 7 * HW;

  float acc[7][2];
#pragma unroll
  for (int oc = 0; oc < 7; ++oc) {
    float bv = bm[oc];
    acc[oc][0] = bv;
    acc[oc][1] = bv;
  }

#pragma unroll 1
  for (int ic = 0; ic < 7; ++ic) {
    float win[3][4];
    const float* plane = cbase + (size_t)ic * HW;
#pragma unroll
    for (int r = 0; r < 3; ++r) {
      int hh = h - 1 + r;
      bool okh = (unsigned)hh < (unsigned)Hn;
      const float* row = plane + hh * Wn;
      if (okh) {
        float2 mid = *(const float2*)(row + w0);
        win[r][0] = (w0 > 0) ? row[w0 - 1] : 0.f;
        win[r][1] = mid.x;
        win[r][2] = mid.y;
        win[r][3] = (w0 + 2 < Wn) ? row[w0 + 2] : 0.f;
      } else {
        win[r][0] = win[r][1] = win[r][2] = win[r][3] = 0.f;
      }
    }
#pragma unroll
    for (int oc = 0; oc < 7; ++oc) {
      const float* wp = Wm + (oc * 7 + ic) * 9;
#pragma unroll
      for (int dy = 0; dy < 3; ++dy) {
#pragma unroll
        for (int dx = 0; dx < 3; ++dx) {
          float wvv = wp[dy * 3 + dx];
          acc[oc][0] = fmaf(wvv, win[dy][0 + dx], acc[oc][0]);
          acc[oc][1] = fmaf(wvv, win[dy][1 + dx], acc[oc][1]);
        }
      }
    }
  }

  float* ob = out + (size_t)b * 7 * HW + h * Wn + w0;
#pragma unroll
  for (int oc = 0; oc < 7; ++oc)
    *(float2*)(ob + (size_t)oc * HW) = make_float2(acc[oc][0], acc[oc][1]);
}

extern "C" void kernel_launch(void* const* d_in, const int* in_sizes, int n_in,
                              void* d_out, int out_size, void* d_ws, size_t ws_size,
                              hipStream_t stream) {
  const float* x  = (const float*)d_in[0];
  const float* W1 = (const float*)d_in[1];
  const float* b1 = (const float*)d_in[2];
  const float* W2 = (const float*)d_in[3];
  const float* b2 = (const float*)d_in[4];
  const float* Wm = (const float*)d_in[5];
  const float* bm = (const float*)d_in[6];
  float* out  = (float*)d_out;
  float* comb = (float*)d_ws;  // 8*7*256*256 floats = 14.7 MB

  sim_kernel<<<6 * 8 * 256, 256, 0, stream>>>(x, W1, b1, W2, b2, comb);
  mix_kernel<<<1024, 256, 0, stream>>>(comb, Wm, bm, out);
}

// Round 8
// 131.035 us; speedup vs baseline: 1.0680x; 1.0680x over previous
//
#include <hip/hip_runtime.h>
#include <math.h>

#define Bn 8
#define Hn 256
#define Wn 256
#define HW (Hn * Wn)
#define ROWS 8

typedef __attribute__((ext_vector_type(8))) short bf16x8;
typedef __attribute__((ext_vector_type(4))) float f32x4;

// Pack two fp32 into packed bf16x2 by truncation: one v_perm_b32.
__device__ __forceinline__ unsigned int pk_bf16(float lo, float hi) {
  return __builtin_amdgcn_perm(__float_as_uint(hi), __float_as_uint(lo),
                               0x07060302u);
}

// Kernel A (R8): fused conv1(2->64,3x3)+ReLU -> conv2(64->1) -> sigmoid ->
// gate, conv1 on bf16 MFMA. R7 was latency/phase-bound (conflicts=0 but
// true VALU ~35%, MFMA 9%: 12288 tiny blocks, 18-load latency window +
// barrier + short compute each). R8: block = (n,b,8-row chunk), 1536 blocks:
//  - ALL 10 raw rows (base+check) staged once in LDS via 5 float4
//    loads/thread (vs 18 scalar loads per row in R7).
//  - weights/afrag/w2/b1 staged once per 8 rows.
//  - per row: pack im2col row r+1 (from LDS rows) into double-buffered
//    tile while computing row r; ONE barrier per row.
//  - im2col = 3 quads + shared zero16 for q=3 (broadcast) -> 48.3 KB LDS,
//    3 blocks/CU.
__global__ __launch_bounds__(256) void sim_kernel(
    const float* __restrict__ x,   // (8,7,256,256)
    const float* __restrict__ W1,  // (6,64,2,3,3)
    const float* __restrict__ b1,  // (6,64)
    const float* __restrict__ W2,  // (6,1,64,1,1)
    const float* __restrict__ b2,  // (6,1)
    float* __restrict__ comb)      // (8,7,256,256)
{
  __shared__ float rows[2][10][256];  // 20 KB raw fp32 rows [plane][j][col]
  __shared__ uint4 imbuf[2][3][256];  // 24 KB im2col double buffer (q=0..2)
  __shared__ uint4 wq[4][64];         // 4 KB A-frags
  __shared__ uint4 zero16;            // q=3 B-frag (broadcast)

  int bi = blockIdx.x;
  int n  = bi >> 8;            // 0..5
  int b  = (bi >> 5) & 7;      // 0..7
  int h0 = (bi & 31) * ROWS;   // chunk start row
  int cc = (n < 3) ? n : n + 1;
  int t = threadIdx.x;

  const float* xb     = x + (size_t)b * 7 * HW;
  const float* basep  = xb + 3 * HW;
  const float* checkp = xb + (size_t)cc * HW;

  // ---- stage A (weights) in MFMA A-layout: t = f*64 + q*16 + m ----
  {
    int f = t >> 6, qq = (t >> 4) & 3, m = t & 15;
    int ch = 16 * f + m;
    int bsrc = (n < 3) ? 0 : 1;  // weight input-ch that multiplies BASE
    const float* wch = W1 + ((size_t)(n * 64 + ch)) * 18;
    unsigned int kv[4];
#pragma unroll
    for (int jj = 0; jj < 4; ++jj) {
      int k0 = qq * 8 + jj * 2, k1 = k0 + 1;
      float v0 = 0.f, v1 = 0.f;
      if (k0 < 18) {
        int src = (k0 < 9) ? bsrc : 1 - bsrc;
        v0 = wch[src * 9 + (k0 < 9 ? k0 : k0 - 9)];
      }
      if (k1 < 18) {
        int src = (k1 < 9) ? bsrc : 1 - bsrc;
        v1 = wch[src * 9 + (k1 < 9 ? k1 : k1 - 9)];
      }
      kv[jj] = pk_bf16(v0, v1);
    }
    wq[f][(qq << 4) + m] = make_uint4(kv[0], kv[1], kv[2], kv[3]);
  }
  if (t == 0) zero16 = make_uint4(0u, 0u, 0u, 0u);

  // ---- per-lane conv2/bias params (global loads, no LDS dep) ----
  int lane = t & 63, wvid = t >> 6;
  int q = lane >> 4, m_ = lane & 15;
  float w2v[4][4], b1v[4][4];
#pragma unroll
  for (int f = 0; f < 4; ++f) {
    float4 tw = *(const float4*)&W2[n * 64 + 16 * f + 4 * q];
    float4 tb = *(const float4*)&b1[n * 64 + 16 * f + 4 * q];
    w2v[f][0] = tw.x; w2v[f][1] = tw.y; w2v[f][2] = tw.z; w2v[f][3] = tw.w;
    b1v[f][0] = tb.x; b1v[f][1] = tb.y; b1v[f][2] = tb.z; b1v[f][3] = tb.w;
  }
  float bb = b2[n];

  // ---- stage raw rows: 20 rows (2 planes x 10) x 256 floats ----
  {
    int col = (t & 63) << 2;
#pragma unroll
    for (int it = 0; it < 5; ++it) {
      int rowflat = it * 4 + (t >> 6);  // 0..19
      int pl = (rowflat >= 10) ? 1 : 0;
      int j  = rowflat - pl * 10;
      int hh = h0 - 1 + j;
      const float* src = pl ? checkp : basep;
      float4 val = make_float4(0.f, 0.f, 0.f, 0.f);
      if ((unsigned)hh < (unsigned)Hn) val = *(const float4*)(src + hh * Wn + col);
      *(float4*)&rows[pl][j][col] = val;
    }
  }
  __syncthreads();

  // A fragments (contiguous 16 B per lane, conflict-free)
  bf16x8 afrag[4];
#pragma unroll
  for (int f = 0; f < 4; ++f) afrag[f] = *(const bf16x8*)&wq[f][lane];

  float* combcc = comb + ((size_t)b * 7 + cc) * HW;
  float* comb3  = comb + ((size_t)b * 7 + 3) * HW;

  // ---- pack row hh into imbuf[dst] (thread t = pixel column) ----
  auto pack = [&](int hh, int dst) {
    int lr = hh - h0 + 1;  // 1..8; window rows lr-1..lr+1 in 0..9
    float v[18];
#pragma unroll
    for (int pl = 0; pl < 2; ++pl) {
#pragma unroll
      for (int rr = 0; rr < 3; ++rr) {
        const float* rp = rows[pl][lr - 1 + rr];
        v[pl * 9 + rr * 3 + 0] = (t > 0) ? rp[t - 1] : 0.f;
        v[pl * 9 + rr * 3 + 1] = rp[t];
        v[pl * 9 + rr * 3 + 2] = (t < 255) ? rp[t + 1] : 0.f;
      }
    }
    if (n == 0) comb3[hh * Wn + t] = v[4];  // combined ch3 = base center
    unsigned int kv[9];
#pragma unroll
    for (int j = 0; j < 9; ++j) kv[j] = pk_bf16(v[2 * j], v[2 * j + 1]);
    imbuf[dst][0][t] = make_uint4(kv[0], kv[1], kv[2], kv[3]);
    imbuf[dst][1][t] = make_uint4(kv[4], kv[5], kv[6], kv[7]);
    imbuf[dst][2][t] = make_uint4(kv[8], 0u, 0u, 0u);
  };

  pack(h0, 0);
  __syncthreads();

#pragma unroll 2
  for (int r = 0; r < ROWS; ++r) {
    int h = h0 + r;
    int cbuf = r & 1;
    if (r < ROWS - 1) pack(h + 1, 1 - cbuf);

    float g[4];
#pragma unroll
    for (int i = 0; i < 4; ++i) {
      int px = (wvid * 4 + i) * 16 + m_;

      f32x4 acc[4];
#pragma unroll
      for (int f = 0; f < 4; ++f) {
        acc[f][0] = b1v[f][0]; acc[f][1] = b1v[f][1];
        acc[f][2] = b1v[f][2]; acc[f][3] = b1v[f][3];
      }

      const uint4* baddr = (q < 3) ? &imbuf[cbuf][q][px] : &zero16;
      bf16x8 bfrag = *(const bf16x8*)baddr;
#pragma unroll
      for (int f = 0; f < 4; ++f)
        acc[f] = __builtin_amdgcn_mfma_f32_16x16x32_bf16(afrag[f], bfrag,
                                                         acc[f], 0, 0, 0);

      float sp = 0.f;
#pragma unroll
      for (int f = 0; f < 4; ++f)
#pragma unroll
        for (int rr = 0; rr < 4; ++rr)
          sp = fmaf(w2v[f][rr], fmaxf(acc[f][rr], 0.f), sp);
      sp += __shfl_xor(sp, 16, 64);
      sp += __shfl_xor(sp, 32, 64);
      sp += bb;

      float e = __builtin_amdgcn_exp2f(sp * -1.442695041f);
      g[i] = __builtin_amdgcn_rcpf(1.f + e);
    }

    // Coalesced store: lane l -> px = wvid*64 + l, gate g[l>>4]
    int hi = lane >> 4;
    float gsel = (hi == 0) ? g[0] : (hi == 1) ? g[1] : (hi == 2) ? g[2] : g[3];
    int pxs = wvid * 64 + lane;
    int lr = r + 1;
    combcc[h * Wn + pxs] = gsel * rows[1][lr][pxs];
    __syncthreads();
  }
}

// Kernel B: final mixing conv (7->7, 3x3, SAME). 2 px/thread, 1024 blocks.
// (Unchanged — never appears in top-5 dispatches.)
__global__ __launch_bounds__(256) void mix_kernel(
    const float* __restrict__ comb,  // (8,7,256,256)
    const float* __restrict__ Wm,    // (7,7,3,3)
    const float* __restrict__ bm,    // (7,)
    float* __restrict__ out)         // (8,7,256,256)
{
  int idx = blockIdx.x * 256 + threadIdx.x;  // over B*H*W/2 = 262144
  int w0 = (idx & 127) << 1;
  int h  = (idx >> 7) & (Hn - 1);
  int b  = idx >> 15;
  const float* cbase = comb + (size_t)b * 7 * HW;

  float acc[7][2];
#pragma unroll
  for (int oc = 0; oc < 7; ++oc) {
    float bv = bm[oc];
    acc[oc][0] = bv;
    acc[oc][1] = bv;
  }

#pragma unroll 1
  for (int ic = 0; ic < 7; ++ic) {
    float win[3][4];
    const float* plane = cbase + (size_t)ic * HW;
#pragma unroll
    for (int r = 0; r < 3; ++r) {
      int hh = h - 1 + r;
      bool okh = (unsigned)hh < (unsigned)Hn;
      const float* row = plane + hh * Wn;
      if (okh) {
        float2 mid = *(const float2*)(row + w0);
        win[r][0] = (w0 > 0) ? row[w0 - 1] : 0.f;
        win[r][1] = mid.x;
        win[r][2] = mid.y;
        win[r][3] = (w0 + 2 < Wn) ? row[w0 + 2] : 0.f;
      } else {
        win[r][0] = win[r][1] = win[r][2] = win[r][3] = 0.f;
      }
    }
#pragma unroll
    for (int oc = 0; oc < 7; ++oc) {
      const float* wp = Wm + (oc * 7 + ic) * 9;
#pragma unroll
      for (int dy = 0; dy < 3; ++dy) {
#pragma unroll
        for (int dx = 0; dx < 3; ++dx) {
          float wvv = wp[dy * 3 + dx];
          acc[oc][0] = fmaf(wvv, win[dy][0 + dx], acc[oc][0]);
          acc[oc][1] = fmaf(wvv, win[dy][1 + dx], acc[oc][1]);
        }
      }
    }
  }

  float* ob = out + (size_t)b * 7 * HW + h * Wn + w0;
#pragma unroll
  for (int oc = 0; oc < 7; ++oc)
    *(float2*)(ob + (size_t)oc * HW) = make_float2(acc[oc][0], acc[oc][1]);
}

extern "C" void kernel_launch(void* const* d_in, const int* in_sizes, int n_in,
                              void* d_out, int out_size, void* d_ws, size_t ws_size,
                              hipStream_t stream) {
  const float* x  = (const float*)d_in[0];
  const float* W1 = (const float*)d_in[1];
  const float* b1 = (const float*)d_in[2];
  const float* W2 = (const float*)d_in[3];
  const float* b2 = (const float*)d_in[4];
  const float* Wm = (const float*)d_in[5];
  const float* bm = (const float*)d_in[6];
  float* out  = (float*)d_out;
  float* comb = (float*)d_ws;  // 8*7*256*256 floats = 14.7 MB

  sim_kernel<<<6 * 8 * (Hn / ROWS), 256, 0, stream>>>(x, W1, b1, W2, b2, comb);
  mix_kernel<<<1024, 256, 0, stream>>>(comb, Wm, bm, out);
}

// Round 9
// 121.598 us; speedup vs baseline: 1.1509x; 1.0776x over previous
//
#include <hip/hip_runtime.h>
#include <math.h>

#define Bn 8
#define Hn 256
#define Wn 256
#define HW (Hn * Wn)
#define ROWS 8
#define RP 264  // padded row length (words); data at [4..259], zeros at 3/260

typedef __attribute__((ext_vector_type(8))) short bf16x8;
typedef __attribute__((ext_vector_type(4))) float f32x4;

// Pack two fp32 (as raw bits) into packed bf16x2 by truncation: one v_perm.
__device__ __forceinline__ unsigned int pk_bits(unsigned int lo,
                                                unsigned int hi) {
  return __builtin_amdgcn_perm(hi, lo, 0x07060302u);
}
__device__ __forceinline__ unsigned int pk_bf16(float lo, float hi) {
  return pk_bits(__float_as_uint(lo), __float_as_uint(hi));
}

// Kernel A (R9): fused conv1(2->64,3x3)+ReLU -> conv2(64->1) -> sigmoid ->
// gate, conv1 on bf16 MFMA.
//
// R8 was still phase/latency-bound (MFMA 9%, occupancy 27%: 49.7 KB LDS,
// per-row barriers locksteping 4 waves). R9 deletes the im2col buffer and
// pack phase entirely: each lane gathers its B-fragment directly from the
// fp32 rows in LDS (8 ds_read_b32 + 4 v_perm per strip; per-lane addresses
// precomputed once, advanced by a uniform offset via one v_mad each, with
// invalid taps (k>=18) pointing at a zero word with a zero increment).
// Rows are padded to 264 words with zero edge words at [3]/[260] -> no
// boundary logic in the inner loop. ONE barrier per block; waves run free.
// LDS = 21.1 + 4.1 KB -> 25.3 KB.
__global__ __launch_bounds__(256) void sim_kernel(
    const float* __restrict__ x,   // (8,7,256,256)
    const float* __restrict__ W1,  // (6,64,2,3,3)
    const float* __restrict__ b1,  // (6,64)
    const float* __restrict__ W2,  // (6,1,64,1,1)
    const float* __restrict__ b2,  // (6,1)
    float* __restrict__ comb)      // (8,7,256,256)
{
  __shared__ float rowsF[2 * 10 * RP];  // 21.1 KB raw fp32 rows, padded
  __shared__ uint4 wq[4][64];           // 4 KB A-frags

  int bi = blockIdx.x;
  int n  = bi >> 8;            // 0..5
  int b  = (bi >> 5) & 7;      // 0..7
  int h0 = (bi & 31) * ROWS;   // chunk start row
  int cc = (n < 3) ? n : n + 1;
  int t = threadIdx.x;

  const float* xb     = x + (size_t)b * 7 * HW;
  const float* basep  = xb + 3 * HW;
  const float* checkp = xb + (size_t)cc * HW;

  // ---- stage weights in MFMA A-layout: t = f*64 + q*16 + m ----
  {
    int f = t >> 6, qq = (t >> 4) & 3, m = t & 15;
    int ch = 16 * f + m;
    int bsrc = (n < 3) ? 0 : 1;  // weight input-ch that multiplies BASE
    const float* wch = W1 + ((size_t)(n * 64 + ch)) * 18;
    unsigned int kv[4];
#pragma unroll
    for (int jj = 0; jj < 4; ++jj) {
      int k0 = qq * 8 + jj * 2, k1 = k0 + 1;
      float v0 = 0.f, v1 = 0.f;
      if (k0 < 18) {
        int src = (k0 < 9) ? bsrc : 1 - bsrc;
        v0 = wch[src * 9 + (k0 < 9 ? k0 : k0 - 9)];
      }
      if (k1 < 18) {
        int src = (k1 < 9) ? bsrc : 1 - bsrc;
        v1 = wch[src * 9 + (k1 < 9 ? k1 : k1 - 9)];
      }
      kv[jj] = pk_bf16(v0, v1);
    }
    wq[f][(qq << 4) + m] = make_uint4(kv[0], kv[1], kv[2], kv[3]);
  }

  // ---- per-lane conv2/bias params (global loads, no LDS dep) ----
  int lane = t & 63, wvid = t >> 6;
  int q = lane >> 4, m_ = lane & 15;
  float w2v[4][4], b1v[4][4];
#pragma unroll
  for (int f = 0; f < 4; ++f) {
    float4 tw = *(const float4*)&W2[n * 64 + 16 * f + 4 * q];
    float4 tb = *(const float4*)&b1[n * 64 + 16 * f + 4 * q];
    w2v[f][0] = tw.x; w2v[f][1] = tw.y; w2v[f][2] = tw.z; w2v[f][3] = tw.w;
    b1v[f][0] = tb.x; b1v[f][1] = tb.y; b1v[f][2] = tb.z; b1v[f][3] = tb.w;
  }
  float bb = b2[n];

  // ---- stage raw rows: 20 rows x 256 cols -> rowsF[rf*RP + 4 + col] ----
  {
    int col = (t & 63) << 2;
#pragma unroll
    for (int it = 0; it < 5; ++it) {
      int rf = it * 4 + (t >> 6);  // 0..19 = pl*10 + j
      int pl = (rf >= 10) ? 1 : 0;
      int j  = rf - pl * 10;
      int hh = h0 - 1 + j;
      const float* src = pl ? checkp : basep;
      float4 val = make_float4(0.f, 0.f, 0.f, 0.f);
      if ((unsigned)hh < (unsigned)Hn)
        val = *(const float4*)(src + hh * Wn + col);
      *(float4*)&rowsF[rf * RP + 4 + col] = val;
    }
    if (t < 20) {  // edge zeros
      rowsF[t * RP + 3] = 0.f;
      rowsF[t * RP + 260] = 0.f;
    }
    if (t == 20) rowsF[0] = 0.f;  // zero word for invalid taps
  }

  // ---- per-lane gather table: 8 taps k = 8q + jh ----
  const unsigned int* rowsU = (const unsigned int*)rowsF;
  unsigned int addr[8], vbit[8];
#pragma unroll
  for (int jh = 0; jh < 8; ++jh) {
    int k = 8 * q + jh;
    if (k < 18) {
      int pl = (k >= 9) ? 1 : 0;
      int rem = k - 9 * pl;
      int rr = rem / 3, dx = rem - rr * 3;
      addr[jh] = (pl * 10 + rr) * RP + 3 + dx + wvid * 64 + m_;
      vbit[jh] = 1u;
    } else {
      addr[jh] = 0u;   // rowsF[0] == 0
      vbit[jh] = 0u;
    }
  }

  __syncthreads();

  // A fragments (contiguous 16 B per lane, conflict-free)
  bf16x8 afrag[4];
#pragma unroll
  for (int f = 0; f < 4; ++f) afrag[f] = *(const bf16x8*)&wq[f][lane];

  float* combcc = comb + ((size_t)b * 7 + cc) * HW;
  float* comb3  = comb + ((size_t)b * 7 + 3) * HW;
  int pxs = wvid * 64 + lane;

#pragma unroll 1
  for (int r = 0; r < ROWS; ++r) {
    int h = h0 + r;

    float g[4];
#pragma unroll
    for (int i = 0; i < 4; ++i) {
      unsigned int offs = (unsigned)(r * RP + i * 16);  // uniform

      unsigned int d[8];
#pragma unroll
      for (int jh = 0; jh < 8; ++jh)
        d[jh] = rowsU[addr[jh] + vbit[jh] * offs];  // mad + ds_read_b32

      union { unsigned int u[4]; bf16x8 v; } bu;
#pragma unroll
      for (int jj = 0; jj < 4; ++jj)
        bu.u[jj] = pk_bits(d[2 * jj], d[2 * jj + 1]);
      bf16x8 bfrag = bu.v;

      f32x4 acc[4];
#pragma unroll
      for (int f = 0; f < 4; ++f) {
        acc[f][0] = b1v[f][0]; acc[f][1] = b1v[f][1];
        acc[f][2] = b1v[f][2]; acc[f][3] = b1v[f][3];
      }
#pragma unroll
      for (int f = 0; f < 4; ++f)
        acc[f] = __builtin_amdgcn_mfma_f32_16x16x32_bf16(afrag[f], bfrag,
                                                         acc[f], 0, 0, 0);

      float sp = 0.f;
#pragma unroll
      for (int f = 0; f < 4; ++f)
#pragma unroll
        for (int rr = 0; rr < 4; ++rr)
          sp = fmaf(w2v[f][rr], fmaxf(acc[f][rr], 0.f), sp);
      sp += __shfl_xor(sp, 16, 64);
      sp += __shfl_xor(sp, 32, 64);
      sp += bb;

      float e = __builtin_amdgcn_exp2f(sp * -1.442695041f);
      g[i] = __builtin_amdgcn_rcpf(1.f + e);
    }

    // Coalesced store: lane l -> px = wvid*64 + l, gate g[l>>4]
    int hi = lane >> 4;
    float gsel = (hi == 0) ? g[0] : (hi == 1) ? g[1] : (hi == 2) ? g[2] : g[3];
    float ccv = rowsF[(10 + r + 1) * RP + 4 + pxs];  // check center
    combcc[h * Wn + pxs] = gsel * ccv;
    if (n == 0) comb3[h * Wn + pxs] = rowsF[(r + 1) * RP + 4 + pxs];
  }
}

// Kernel B (R9): final mixing conv (7->7, 3x3, SAME), LDS-staged.
// Block = (b, 4-row chunk) -> 512 blocks. Stage 7 planes x 6 padded rows
// fp32 (43.3 KB, 3 blocks/CU); thread = (row r = t>>6, 4 px). ic rolled
// (63 uniform s_load weights/iter, fits SGPRs); oc/taps/px unrolled.
// Pure-FLOP cost is ~3 us; this form removes the per-px scalar VMEM that
// made the old version latency-bound.
__global__ __launch_bounds__(256) void mix_kernel(
    const float* __restrict__ comb,  // (8,7,256,256)
    const float* __restrict__ Wm,    // (7,7,3,3)
    const float* __restrict__ bm,    // (7,)
    float* __restrict__ out)         // (8,7,256,256)
{
  __shared__ float mr[7 * 6 * RP];  // 43.3 KB

  int bi = blockIdx.x;              // 0..511
  int b  = bi >> 6;
  int h0 = (bi & 63) << 2;
  int t = threadIdx.x;

  // stage: 42 rows x 64 float4
  for (int u = t; u < 42 * 64; u += 256) {
    int rf = u >> 6;               // 0..41 = ic*6 + j
    int col = (u & 63) << 2;
    int ic = rf / 6, j = rf - ic * 6;
    int hh = h0 - 1 + j;
    float4 v = make_float4(0.f, 0.f, 0.f, 0.f);
    if ((unsigned)hh < (unsigned)Hn)
      v = *(const float4*)(comb + ((size_t)b * 7 + ic) * HW + hh * Wn + col);
    *(float4*)&mr[rf * RP + 4 + col] = v;
  }
  if (t < 42) {
    mr[t * RP + 3] = 0.f;
    mr[t * RP + 260] = 0.f;
  }
  __syncthreads();

  int r   = t >> 6;          // local row 0..3
  int px0 = (t & 63) << 2;   // 0..252
  int h   = h0 + r;

  float acc[7][4];
#pragma unroll
  for (int oc = 0; oc < 7; ++oc) {
    float bv = bm[oc];
#pragma unroll
    for (int p = 0; p < 4; ++p) acc[oc][p] = bv;
  }

#pragma unroll 1
  for (int ic = 0; ic < 7; ++ic) {
    // 3 rows x 12 cols (indices px0..px0+11 cover needed [px0+3, px0+8])
    float w[3][12];
#pragma unroll
    for (int dy = 0; dy < 3; ++dy) {
      const float* rp = &mr[(ic * 6 + r + dy) * RP];
      *(float4*)&w[dy][0] = *(const float4*)(rp + px0);
      *(float4*)&w[dy][4] = *(const float4*)(rp + px0 + 4);
      *(float4*)&w[dy][8] = *(const float4*)(rp + px0 + 8);
    }
    const float* wp = Wm + ic * 9;  // + oc*63
#pragma unroll
    for (int oc = 0; oc < 7; ++oc) {
      const float* wo = wp + oc * 63;
#pragma unroll
      for (int dy = 0; dy < 3; ++dy)
#pragma unroll
        for (int dx = 0; dx < 3; ++dx) {
          float wvv = wo[dy * 3 + dx];
#pragma unroll
          for (int p = 0; p < 4; ++p)
            acc[oc][p] = fmaf(wvv, w[dy][3 + p + dx], acc[oc][p]);
        }
    }
  }

  float* ob = out + (size_t)b * 7 * HW + h * Wn + px0;
#pragma unroll
  for (int oc = 0; oc < 7; ++oc)
    *(float4*)(ob + (size_t)oc * HW) =
        make_float4(acc[oc][0], acc[oc][1], acc[oc][2], acc[oc][3]);
}

extern "C" void kernel_launch(void* const* d_in, const int* in_sizes, int n_in,
                              void* d_out, int out_size, void* d_ws, size_t ws_size,
                              hipStream_t stream) {
  const float* x  = (const float*)d_in[0];
  const float* W1 = (const float*)d_in[1];
  const float* b1 = (const float*)d_in[2];
  const float* W2 = (const float*)d_in[3];
  const float* b2 = (const float*)d_in[4];
  const float* Wm = (const float*)d_in[5];
  const float* bm = (const float*)d_in[6];
  float* out  = (float*)d_out;
  float* comb = (float*)d_ws;  // 8*7*256*256 floats = 14.7 MB

  sim_kernel<<<6 * 8 * (Hn / ROWS), 256, 0, stream>>>(x, W1, b1, W2, b2, comb);
  mix_kernel<<<8 * (Hn / 4), 256, 0, stream>>>(comb, Wm, bm, out);
}

// Round 10
// 119.891 us; speedup vs baseline: 1.1673x; 1.0142x over previous
//
#include <hip/hip_runtime.h>
#include <math.h>

#define Bn 8
#define Hn 256
#define Wn 256
#define HW (Hn * Wn)
#define ROWS 8
#define RP 264  // padded row length (words); data at [4..259], zeros at 3/260
#define ZW (20 * RP)  // zero region: rowsF[ZW .. ZW+63] == 0

typedef __attribute__((ext_vector_type(8))) short bf16x8;
typedef __attribute__((ext_vector_type(4))) float f32x4;

// Pack two fp32 (raw bits) into packed bf16x2 by truncation: one v_perm.
__device__ __forceinline__ unsigned int pk_bits(unsigned int lo,
                                                unsigned int hi) {
  return __builtin_amdgcn_perm(hi, lo, 0x07060302u);
}
__device__ __forceinline__ unsigned int pk_bf16(float lo, float hi) {
  return pk_bits(__float_as_uint(lo), __float_as_uint(hi));
}

// k-slot -> tap mapping (tap = pl*9 + rr*3 + dx), chosen so that on every
// gather instruction q0 and q1 hit DISJOINT 16-bank halves:
//   pairs (pl,rr=0,dx)<->(pl,rr=2,dx): addr delta 2*RP=528 == 16 (mod 32)
//   pairs (pl0,rr=1,dx)<->(pl1,rr=1,dx): delta 10*RP=2640 == 16 (mod 32)
// q0 slots jh=0..7 take pair-firsts, q1 the pair-seconds, q2 jh=0,1 the
// leftover 9th pair; q2 jh>=2 and all q3 read the zero region (broadcast).
__device__ __constant__ const int T0c[8] = {0, 1, 2, 9, 10, 11, 3, 4};
__device__ __constant__ const int T1c[8] = {6, 7, 8, 15, 16, 17, 12, 13};
__device__ __constant__ const int T2c[8] = {5, 14, -1, -1, -1, -1, -1, -1};

// Kernel A (R10): fused conv1(2->64,3x3)+ReLU -> conv2(64->1) -> sigmoid ->
// gate, conv1 on bf16 MFMA, direct LDS gather (no im2col buffer).
// R10 vs R9 (43 us, 1.78M bank conflicts, MFMA 11%):
//  - conflict-free k-remap (see above)
//  - strips gathered in pairs via ds_read2_b32 (offsets {0,16},{32,48} words
//    from one vaddr) -> LDS instructions per row halved
//  - MFMA C-operand = b1 vector directly (no 16 acc-init movs per strip)
__global__ __launch_bounds__(256) void sim_kernel(
    const float* __restrict__ x,   // (8,7,256,256)
    const float* __restrict__ W1,  // (6,64,2,3,3)
    const float* __restrict__ b1,  // (6,64)
    const float* __restrict__ W2,  // (6,1,64,1,1)
    const float* __restrict__ b2,  // (6,1)
    float* __restrict__ comb)      // (8,7,256,256)
{
  __shared__ float rowsF[20 * RP + 64];  // 21.4 KB rows + zero region
  __shared__ uint4 wq[4][64];            // 4 KB A-frags

  int bi = blockIdx.x;
  int n  = bi >> 8;            // 0..5
  int b  = (bi >> 5) & 7;      // 0..7
  int h0 = (bi & 31) * ROWS;   // chunk start row
  int cc = (n < 3) ? n : n + 1;
  int t = threadIdx.x;

  const float* xb     = x + (size_t)b * 7 * HW;
  const float* basep  = xb + 3 * HW;
  const float* checkp = xb + (size_t)cc * HW;

  // ---- stage weights in MFMA A-layout with the k-remap ----
  {
    int f = t >> 6, qq = (t >> 4) & 3, m = t & 15;
    int bsrc = (n < 3) ? 0 : 1;  // weight input-ch that multiplies BASE
    const float* wch = W1 + ((size_t)(n * 64 + 16 * f + m)) * 18;
    unsigned int kv[4];
#pragma unroll
    for (int jj = 0; jj < 4; ++jj) {
      int ja = 2 * jj, jb = 2 * jj + 1;
      int ta = (qq == 0) ? T0c[ja] : (qq == 1) ? T1c[ja]
               : (qq == 2) ? T2c[ja] : -1;
      int tb = (qq == 0) ? T0c[jb] : (qq == 1) ? T1c[jb]
               : (qq == 2) ? T2c[jb] : -1;
      float va = 0.f, vb = 0.f;
      if (ta >= 0) {
        int pl = ta / 9, rem = ta - pl * 9;
        va = wch[(pl ? 1 - bsrc : bsrc) * 9 + rem];
      }
      if (tb >= 0) {
        int pl = tb / 9, rem = tb - pl * 9;
        vb = wch[(pl ? 1 - bsrc : bsrc) * 9 + rem];
      }
      kv[jj] = pk_bf16(va, vb);
    }
    wq[f][(qq << 4) + m] = make_uint4(kv[0], kv[1], kv[2], kv[3]);
  }

  // ---- per-lane conv2/bias params (global loads, no LDS dep) ----
  int lane = t & 63, wvid = t >> 6;
  int q = lane >> 4, m_ = lane & 15;
  float w2v[4][4];
  f32x4 b1vv[4];
#pragma unroll
  for (int f = 0; f < 4; ++f) {
    float4 tw = *(const float4*)&W2[n * 64 + 16 * f + 4 * q];
    float4 tb = *(const float4*)&b1[n * 64 + 16 * f + 4 * q];
    w2v[f][0] = tw.x; w2v[f][1] = tw.y; w2v[f][2] = tw.z; w2v[f][3] = tw.w;
    b1vv[f][0] = tb.x; b1vv[f][1] = tb.y;
    b1vv[f][2] = tb.z; b1vv[f][3] = tb.w;
  }
  float bb = b2[n];

  // ---- stage raw rows: 20 rows x 256 cols -> rowsF[rf*RP + 4 + col] ----
  {
    int col = (t & 63) << 2;
#pragma unroll
    for (int it = 0; it < 5; ++it) {
      int rf = it * 4 + (t >> 6);  // 0..19 = pl*10 + j
      int pl = (rf >= 10) ? 1 : 0;
      int j  = rf - pl * 10;
      int hh = h0 - 1 + j;
      const float* src = pl ? checkp : basep;
      float4 val = make_float4(0.f, 0.f, 0.f, 0.f);
      if ((unsigned)hh < (unsigned)Hn)
        val = *(const float4*)(src + hh * Wn + col);
      *(float4*)&rowsF[rf * RP + 4 + col] = val;
    }
    if (t < 20) {  // edge zeros
      rowsF[t * RP + 3] = 0.f;
      rowsF[t * RP + 260] = 0.f;
    }
    if (t >= 192) rowsF[ZW + (t - 192)] = 0.f;  // zero region (64 words)
  }

  // ---- per-lane gather table: slot jh (k = 8q + jh) ----
  const unsigned int* rowsU = (const unsigned int*)rowsF;
  unsigned int addr[8], vbit[8];
#pragma unroll
  for (int jh = 0; jh < 8; ++jh) {
    int tap = (q == 0) ? T0c[jh] : (q == 1) ? T1c[jh]
              : (q == 2) ? T2c[jh] : -1;
    if (tap >= 0) {
      int pl = tap / 9, rem = tap - pl * 9;
      int rr = rem / 3, dx = rem - rr * 3;
      addr[jh] = (pl * 10 + rr) * RP + 3 + dx + wvid * 64 + m_;
      vbit[jh] = 1u;
    } else {
      addr[jh] = (unsigned)ZW;  // zero region; +16/32/48 also zero
      vbit[jh] = 0u;
    }
  }

  __syncthreads();

  // A fragments (contiguous 16 B per lane, conflict-free)
  bf16x8 afrag[4];
#pragma unroll
  for (int f = 0; f < 4; ++f) afrag[f] = *(const bf16x8*)&wq[f][lane];

  float* combcc = comb + ((size_t)b * 7 + cc) * HW;
  float* comb3  = comb + ((size_t)b * 7 + 3) * HW;
  int pxs = wvid * 64 + lane;

#pragma unroll 1
  for (int r = 0; r < ROWS; ++r) {
    int h = h0 + r;
    unsigned int rowoff = (unsigned)(r * RP);

    unsigned int base[8];
#pragma unroll
    for (int jh = 0; jh < 8; ++jh) base[jh] = addr[jh] + vbit[jh] * rowoff;

    float g[4];
#pragma unroll
    for (int half = 0; half < 2; ++half) {
      // gather strip pair (2*half, 2*half+1): one vaddr, imm offsets
      // {32*half, 32*half+16} words -> ds_read2_b32
      unsigned int dlo[8], dhi[8];
#pragma unroll
      for (int jh = 0; jh < 8; ++jh) {
        dlo[jh] = rowsU[base[jh] + half * 32];
        dhi[jh] = rowsU[base[jh] + half * 32 + 16];
      }
#pragma unroll
      for (int j = 0; j < 2; ++j) {
        const unsigned int* d = j ? dhi : dlo;
        union { unsigned int u[4]; bf16x8 v; } bu;
#pragma unroll
        for (int jj = 0; jj < 4; ++jj)
          bu.u[jj] = pk_bits(d[2 * jj], d[2 * jj + 1]);

        f32x4 acc[4];
#pragma unroll
        for (int f = 0; f < 4; ++f)
          acc[f] = __builtin_amdgcn_mfma_f32_16x16x32_bf16(afrag[f], bu.v,
                                                           b1vv[f], 0, 0, 0);

        float sp = 0.f;
#pragma unroll
        for (int f = 0; f < 4; ++f)
#pragma unroll
          for (int rr = 0; rr < 4; ++rr)
            sp = fmaf(w2v[f][rr], fmaxf(acc[f][rr], 0.f), sp);
        sp += __shfl_xor(sp, 16, 64);
        sp += __shfl_xor(sp, 32, 64);
        sp += bb;

        float e = __builtin_amdgcn_exp2f(sp * -1.442695041f);
        g[2 * half + j] = __builtin_amdgcn_rcpf(1.f + e);
      }
    }

    // Coalesced store: lane l -> px = wvid*64 + l, gate g[l>>4]
    int hi = lane >> 4;
    float gsel = (hi == 0) ? g[0] : (hi == 1) ? g[1] : (hi == 2) ? g[2] : g[3];
    float ccv = rowsF[(10 + r + 1) * RP + 4 + pxs];  // check center
    combcc[h * Wn + pxs] = gsel * ccv;
    if (n == 0) comb3[h * Wn + pxs] = rowsF[(r + 1) * RP + 4 + pxs];
  }
}

// Kernel B (R10): final mixing conv (7->7, 3x3, SAME), LDS-staged.
// Block = (b, 2-row chunk) -> 1024 blocks (4 blocks/CU, 16 waves/CU).
// LDS = 7 planes x 4 rows x RP = 29.6 KB. Thread = (row, 2 px).
__global__ __launch_bounds__(256) void mix_kernel(
    const float* __restrict__ comb,  // (8,7,256,256)
    const float* __restrict__ Wm,    // (7,7,3,3)
    const float* __restrict__ bm,    // (7,)
    float* __restrict__ out)         // (8,7,256,256)
{
  __shared__ float mr[28 * RP];  // 29.6 KB

  int bi = blockIdx.x;           // 0..1023
  int b  = bi >> 7;
  int h0 = (bi & 127) << 1;
  int t = threadIdx.x;

  // stage: 28 rows (ic*4 + j) x 64 float4
  for (int u = t; u < 28 * 64; u += 256) {
    int rf = u >> 6;             // 0..27 = ic*4 + j
    int col = (u & 63) << 2;
    int ic = rf >> 2, j = rf & 3;
    int hh = h0 - 1 + j;
    float4 v = make_float4(0.f, 0.f, 0.f, 0.f);
    if ((unsigned)hh < (unsigned)Hn)
      v = *(const float4*)(comb + ((size_t)b * 7 + ic) * HW + hh * Wn + col);
    *(float4*)&mr[rf * RP + 4 + col] = v;
  }
  if (t < 28) {
    mr[t * RP + 3] = 0.f;
    mr[t * RP + 260] = 0.f;
  }
  __syncthreads();

  int r   = t >> 7;           // local row 0..1
  int px0 = (t & 127) << 1;   // 0..254
  int h   = h0 + r;

  float acc[7][2];
#pragma unroll
  for (int oc = 0; oc < 7; ++oc) {
    float bv = bm[oc];
    acc[oc][0] = bv;
    acc[oc][1] = bv;
  }

#pragma unroll 1
  for (int ic = 0; ic < 7; ++ic) {
    float w[3][4];
#pragma unroll
    for (int dy = 0; dy < 3; ++dy) {
      const float* rp = &mr[(ic * 4 + r + dy) * RP + 3 + px0];
      w[dy][0] = rp[0]; w[dy][1] = rp[1];  // adjacent -> ds_read2
      w[dy][2] = rp[2]; w[dy][3] = rp[3];
    }
    const float* wp = Wm + ic * 9;
#pragma unroll
    for (int oc = 0; oc < 7; ++oc) {
      const float* wo = wp + oc * 63;
#pragma unroll
      for (int dy = 0; dy < 3; ++dy)
#pragma unroll
        for (int dx = 0; dx < 3; ++dx) {
          float wvv = wo[dy * 3 + dx];
          acc[oc][0] = fmaf(wvv, w[dy][0 + dx], acc[oc][0]);
          acc[oc][1] = fmaf(wvv, w[dy][1 + dx], acc[oc][1]);
        }
    }
  }

  float* ob = out + (size_t)b * 7 * HW + h * Wn + px0;
#pragma unroll
  for (int oc = 0; oc < 7; ++oc)
    *(float2*)(ob + (size_t)oc * HW) = make_float2(acc[oc][0], acc[oc][1]);
}

extern "C" void kernel_launch(void* const* d_in, const int* in_sizes, int n_in,
                              void* d_out, int out_size, void* d_ws, size_t ws_size,
                              hipStream_t stream) {
  const float* x  = (const float*)d_in[0];
  const float* W1 = (const float*)d_in[1];
  const float* b1 = (const float*)d_in[2];
  const float* W2 = (const float*)d_in[3];
  const float* b2 = (const float*)d_in[4];
  const float* Wm = (const float*)d_in[5];
  const float* bm = (const float*)d_in[6];
  float* out  = (float*)d_out;
  float* comb = (float*)d_ws;  // 8*7*256*256 floats = 14.7 MB

  sim_kernel<<<6 * 8 * (Hn / ROWS), 256, 0, stream>>>(x, W1, b1, W2, b2, comb);
  mix_kernel<<<8 * (Hn / 2), 256, 0, stream>>>(comb, Wm, bm, out);
}